// Round 1
// baseline (408.468 us; speedup 1.0000x reference)
//
#include <hip/hip_runtime.h>

// OctreeDWConvBn: out[n,c] = BN_c( sum_k data[neigh[n,k],c] * weight[k,c] )
// N=131072, C=192, K=27. fp32 in/out; gathered operand staged as bf16.
// R6: R5 structure + non-temporal cache hints on all streaming (read-once /
// write-once) paths, so L2/L3 capacity is reserved for the random-gather
// working set (data_bf, 50 MB, ~27x reuse per row).
//   1) cvt_zero  : NT-load fp32 data (dead after staging), NT-store bf16? no:
//                  data_bf IS the gather target -> cached store. Zero stats.
//   2) conv_r4   : gathers cached; conv_bf result NT-stored (read once later).
//   3) bn_apply_fused : NT-load conv_bf, NT-store out (both touched once).

static constexpr int NN = 131072;   // nodes
static constexpr int CC = 192;      // channels
static constexpr int KK = 27;       // stencil taps
static constexpr int NB = 32;       // nodes per block (serial)
static constexpr float BN_EPS = 1e-5f;

typedef float          f32x4 __attribute__((ext_vector_type(4)));
typedef unsigned short u16x4 __attribute__((ext_vector_type(4)));
typedef unsigned int   u32x2 __attribute__((ext_vector_type(2)));

__device__ __forceinline__ unsigned short f2bf_rne(float x) {
    unsigned u = __float_as_uint(x);
    return (unsigned short)((u + 0x7FFFu + ((u >> 16) & 1u)) >> 16);
}

// ---------------------------------------------------------------------------
// Kernel 1: fp32 -> bf16 staging of `data`, plus zeroing the stat buffers.
// fp32 source is dead after this kernel -> non-temporal loads keep the
// 100 MB stream from evicting useful lines ahead of the conv.
// data_bf store stays CACHED: it is the conv's gather target.
// ---------------------------------------------------------------------------
__global__ __launch_bounds__(256) void cvt_zero(
    const float* __restrict__ src, unsigned short* __restrict__ dst,
    float* __restrict__ stats /* [2*CC] sum|sumsq */)
{
    if (blockIdx.x < 2 && threadIdx.x < CC)
        stats[blockIdx.x * CC + threadIdx.x] = 0.f;

    const int i = blockIdx.x * 256 + threadIdx.x;     // float4 index
    const f32x4 v =
        __builtin_nontemporal_load(reinterpret_cast<const f32x4*>(src) + i);
    u16x4 o;
    o.x = f2bf_rne(v.x); o.y = f2bf_rne(v.y);
    o.z = f2bf_rne(v.z); o.w = f2bf_rne(v.w);
    reinterpret_cast<u16x4*>(dst)[i] = o;
}

// ---------------------------------------------------------------------------
// Kernel 2: depthwise conv + per-block partial BN sums.
// Block = 192 threads (thread = channel). Per node: batch-issue all 27
// gather loads into r[27], then FMA against LDS-held weights. Neighbor
// indices are block-uniform -> scalar loads. Conv result NT-stored bf16
// (it is re-read exactly once, by bn_apply; keeping its dirty lines out of
// L2 leaves the full 4 MB/XCD for gather rows).
// ---------------------------------------------------------------------------
__global__ __launch_bounds__(192, 8) void conv_r4(
    const unsigned short* __restrict__ data_bf,   // [NN, CC] bf16 bits
    const int*   __restrict__ neigh,              // [NN, KK]
    const float* __restrict__ weight,             // [KK, CC]
    unsigned short* __restrict__ conv_bf,         // [NN, CC] bf16 bits (ws)
    float*       __restrict__ ch_sum,             // [CC]
    float*       __restrict__ ch_sumsq)           // [CC]
{
    __shared__ float lds_w[KK * CC];              // 20736 B

    const int c    = threadIdx.x;
    const int base = blockIdx.x * NB;

#pragma unroll
    for (int k = 0; k < KK; ++k) lds_w[k * CC + c] = weight[k * CC + c];
    __syncthreads();

    float s = 0.f, ss = 0.f;

    for (int n = 0; n < NB; ++n) {
        const int node = base + n;                  // block-uniform
        const int* nrow = neigh + node * KK;        // uniform -> s_load

        unsigned short r[KK];
#pragma unroll
        for (int k = 0; k < KK; ++k)
            r[k] = data_bf[(size_t)nrow[k] * CC + c];

        float acc = 0.f;
#pragma unroll
        for (int k = 0; k < KK; ++k)
            acc = fmaf(__uint_as_float((unsigned)r[k] << 16),
                       lds_w[k * CC + c], acc);

        __builtin_nontemporal_store(f2bf_rne(acc),
                                    &conv_bf[(size_t)node * CC + c]);
        s  += acc;
        ss += acc * acc;
    }

    atomicAdd(&ch_sum[c],   s);
    atomicAdd(&ch_sumsq[c], ss);
}

// ---------------------------------------------------------------------------
// Kernel 3: fused BN finalize + normalize.
// Block = 192 threads: t = g*48 + q, q = fixed channel-quad, g = node
// subgroup 0..3. Per-thread scale/bias computed once from channel stats,
// then grid-stride: NT-read uint2 (4 bf16), NT-write float4 (both are
// single-touch streams).
// ---------------------------------------------------------------------------
__global__ __launch_bounds__(192) void bn_apply_fused(
    const unsigned int* __restrict__ conv_bf,   // [NN*96] u32 pairs
    const float* __restrict__ ch_sum,
    const float* __restrict__ ch_sumsq,
    const float* __restrict__ gamma,
    const float* __restrict__ beta,
    float* __restrict__ out)             // [NN, CC]
{
    const int t = threadIdx.x;
    const int g = t / 48;          // node subgroup 0..3
    const int q = t - g * 48;      // channel quad 0..47 (fixed per thread)
    const int cb = q * 4;

    const float inv_n = 1.0f / (float)NN;
    f32x4 sc, bi;
    {
        float m0 = ch_sum[cb + 0] * inv_n, m1 = ch_sum[cb + 1] * inv_n;
        float m2 = ch_sum[cb + 2] * inv_n, m3 = ch_sum[cb + 3] * inv_n;
        float v0 = ch_sumsq[cb + 0] * inv_n - m0 * m0;
        float v1 = ch_sumsq[cb + 1] * inv_n - m1 * m1;
        float v2 = ch_sumsq[cb + 2] * inv_n - m2 * m2;
        float v3 = ch_sumsq[cb + 3] * inv_n - m3 * m3;
        sc.x = gamma[cb + 0] * rsqrtf(v0 + BN_EPS);
        sc.y = gamma[cb + 1] * rsqrtf(v1 + BN_EPS);
        sc.z = gamma[cb + 2] * rsqrtf(v2 + BN_EPS);
        sc.w = gamma[cb + 3] * rsqrtf(v3 + BN_EPS);
        bi.x = beta[cb + 0] - m0 * sc.x;
        bi.y = beta[cb + 1] - m1 * sc.y;
        bi.z = beta[cb + 2] - m2 * sc.z;
        bi.w = beta[cb + 3] - m3 * sc.w;
    }

    // Grid-stride over groups of 4 nodes.
    for (int nb = blockIdx.x; nb < NN / 4; nb += gridDim.x) {
        const int node = nb * 4 + g;
        const int i = node * 48 + q;
        const u32x2 u = __builtin_nontemporal_load(
            reinterpret_cast<const u32x2*>(conv_bf) + i);
        f32x4 v;
        v.x = fmaf(__uint_as_float(u.x << 16),         sc.x, bi.x);
        v.y = fmaf(__uint_as_float(u.x & 0xFFFF0000u), sc.y, bi.y);
        v.z = fmaf(__uint_as_float(u.y << 16),         sc.z, bi.z);
        v.w = fmaf(__uint_as_float(u.y & 0xFFFF0000u), sc.w, bi.w);
        __builtin_nontemporal_store(v, reinterpret_cast<f32x4*>(out) + i);
    }
}

// ---------------------------------------------------------------------------
// Fallback tier (ws too small): fp32 conv + fused apply on fp32.
// ---------------------------------------------------------------------------
__global__ __launch_bounds__(CC) void conv_bn_partial_f32(
    const float* __restrict__ data,
    const int*   __restrict__ neigh,
    const float* __restrict__ weight,
    float*       __restrict__ conv_out,
    float*       __restrict__ ch_sum,
    float*       __restrict__ ch_sumsq)
{
    const int c = threadIdx.x;
    const int base = blockIdx.x * NB;
    float w[KK];
#pragma unroll
    for (int k = 0; k < KK; ++k) w[k] = weight[k * CC + c];
    float s = 0.f, ss = 0.f;
    for (int n = 0; n < NB; ++n) {
        const int node = base + n;
        const int* nrow = neigh + node * KK;
        float acc = 0.f;
#pragma unroll
        for (int k = 0; k < KK; ++k)
            acc = fmaf(data[nrow[k] * CC + c], w[k], acc);
        conv_out[node * CC + c] = acc;
        s += acc; ss += acc * acc;
    }
    atomicAdd(&ch_sum[c], s);
    atomicAdd(&ch_sumsq[c], ss);
}

__global__ __launch_bounds__(192) void bn_apply_f32_fused(
    float* __restrict__ out,
    const float* __restrict__ ch_sum,
    const float* __restrict__ ch_sumsq,
    const float* __restrict__ gamma,
    const float* __restrict__ beta)
{
    const int t = threadIdx.x;
    const int g = t / 48;
    const int q = t - g * 48;
    const int cb = q * 4;
    const float inv_n = 1.0f / (float)NN;
    float4 sc, bi;
    float m0 = ch_sum[cb+0]*inv_n, m1 = ch_sum[cb+1]*inv_n;
    float m2 = ch_sum[cb+2]*inv_n, m3 = ch_sum[cb+3]*inv_n;
    sc.x = gamma[cb+0]*rsqrtf(ch_sumsq[cb+0]*inv_n - m0*m0 + BN_EPS);
    sc.y = gamma[cb+1]*rsqrtf(ch_sumsq[cb+1]*inv_n - m1*m1 + BN_EPS);
    sc.z = gamma[cb+2]*rsqrtf(ch_sumsq[cb+2]*inv_n - m2*m2 + BN_EPS);
    sc.w = gamma[cb+3]*rsqrtf(ch_sumsq[cb+3]*inv_n - m3*m3 + BN_EPS);
    bi.x = beta[cb+0] - m0*sc.x; bi.y = beta[cb+1] - m1*sc.y;
    bi.z = beta[cb+2] - m2*sc.z; bi.w = beta[cb+3] - m3*sc.w;
    for (int nb = blockIdx.x; nb < NN / 4; nb += gridDim.x) {
        const int i = (nb * 4 + g) * 48 + q;
        float4 v = reinterpret_cast<float4*>(out)[i];
        v.x = fmaf(v.x, sc.x, bi.x); v.y = fmaf(v.y, sc.y, bi.y);
        v.z = fmaf(v.z, sc.z, bi.z); v.w = fmaf(v.w, sc.w, bi.w);
        reinterpret_cast<float4*>(out)[i] = v;
    }
}

extern "C" void kernel_launch(void* const* d_in, const int* in_sizes, int n_in,
                              void* d_out, int out_size, void* d_ws, size_t ws_size,
                              hipStream_t stream) {
    const float* data   = (const float*)d_in[0];
    const int*   neigh  = (const int*)  d_in[1];
    const float* weight = (const float*)d_in[2];
    const float* gamma  = (const float*)d_in[3];
    const float* beta   = (const float*)d_in[4];
    float* out = (float*)d_out;

    // ws: stats 2*CC floats (padded to 4096 B) | data_bf 50.3 MB | conv_bf 50.3 MB
    float* stats    = (float*)d_ws;          // [0..191]=sum, [192..383]=sumsq
    float* ch_sum   = stats;
    float* ch_sumsq = stats + CC;
    unsigned short* data_bf = (unsigned short*)((char*)d_ws + 4096);
    const size_t stage_bytes = (size_t)NN * CC * sizeof(unsigned short);
    unsigned short* conv_bf =
        (unsigned short*)((char*)d_ws + 4096 + stage_bytes);

    const size_t need_full = 4096 + 2 * stage_bytes;
    const int vec_grid = (NN * CC / 4) / 256;   // 24576

    if (ws_size >= need_full) {
        cvt_zero<<<vec_grid, 256, 0, stream>>>(data, data_bf, stats);
        conv_r4<<<NN / NB, 192, 0, stream>>>(
            data_bf, neigh, weight, conv_bf, ch_sum, ch_sumsq);
        bn_apply_fused<<<8192, 192, 0, stream>>>(
            (const unsigned int*)conv_bf, ch_sum, ch_sumsq, gamma, beta, out);
    } else {
        hipMemsetAsync(stats, 0, 2 * CC * sizeof(float), stream);
        conv_bn_partial_f32<<<NN / NB, CC, 0, stream>>>(
            data, neigh, weight, out, ch_sum, ch_sumsq);
        bn_apply_f32_fused<<<8192, 192, 0, stream>>>(
            out, ch_sum, ch_sumsq, gamma, beta);
    }
}